// Round 1
// baseline (1947.747 us; speedup 1.0000x reference)
//
#include <hip/hip_runtime.h>
#include <hip/hip_bf16.h>

#define BB 16
#define NPG 512
#define CC 128
#define HH 8
#define LL 4
#define FFN 512
#define NCLS 4
#define DD 16
#define TT 513            // NPG + 1
#define EE 131072         // B * 8192
#define NNODES 8192       // B * NPG

static constexpr size_t BIAS_SZ = (size_t)BB * HH * TT * TT;   // 33,685,632
static constexpr size_t XROWS   = (size_t)BB * TT;             // 8208
static constexpr size_t XSZ     = XROWS * CC;                  // 1,050,624
static constexpr size_t MIDSZ   = XROWS * FFN;                 // 4,202,496

__device__ __forceinline__ float gelu_exact(float v) {
    return 0.5f * v * (1.0f + erff(v * 0.70710678118654752440f));
}
__device__ __forceinline__ float dot4(float4 a, float4 b) {
    return a.x*b.x + a.y*b.y + a.z*b.z + a.w*b.w;
}
__device__ __forceinline__ void fma4(float4& o, float p, float4 v) {
    o.x = fmaf(p, v.x, o.x); o.y = fmaf(p, v.y, o.y);
    o.z = fmaf(p, v.z, o.z); o.w = fmaf(p, v.w, o.w);
}

// ---------------- degree count ----------------
__global__ __launch_bounds__(256) void deg_kernel(const int* __restrict__ ei,
                                                  int* __restrict__ deg_in,
                                                  int* __restrict__ deg_out) {
    int e = blockIdx.x * 256 + threadIdx.x;
    if (e >= EE) return;
    atomicAdd(&deg_out[ei[e]], 1);
    atomicAdd(&deg_in[ei[EE + e]], 1);
}

// ---------------- node encode + graph token ----------------
__global__ __launch_bounds__(256) void encode_kernel(const float* __restrict__ nf,
                                                     const float* __restrict__ Wn,
                                                     const float* __restrict__ bn,
                                                     const float* __restrict__ gt,
                                                     const float* __restrict__ ide,
                                                     const float* __restrict__ ode,
                                                     const int* __restrict__ deg_in,
                                                     const int* __restrict__ deg_out,
                                                     float* __restrict__ x) {
    int gid = blockIdx.x * 256 + threadIdx.x;
    if (gid >= (int)(XROWS * CC)) return;
    int c = gid & (CC - 1);
    int row = gid >> 7;
    int b = row / TT;
    int t = row - b * TT;
    float val;
    if (t == 0) {
        val = gt[c];
    } else {
        int i = b * NPG + t - 1;
        val = bn[c] + nf[i*3+0]*Wn[0*CC + c] + nf[i*3+1]*Wn[1*CC + c] + nf[i*3+2]*Wn[2*CC + c];
        int di = min(deg_in[i], 511);
        int dو = min(deg_out[i], 511);
        val += ide[(size_t)di * CC + c] + ode[(size_t)dو * CC + c];
    }
    x[(size_t)row * CC + c] = val;
}

// ---------------- bias init: biasT[bh][s][q] ----------------
__global__ __launch_bounds__(256) void bias_init_kernel(const float* __restrict__ vb,
                                                        float* __restrict__ biasT) {
    int bh = blockIdx.y;
    int idx = blockIdx.x * 256 + threadIdx.x;
    if (idx >= TT * TT) return;
    int s = idx / TT;
    int q = idx - s * TT;
    float val = (s == 0 || q == 0) ? vb[bh & (HH - 1)] : 0.0f;
    biasT[(size_t)bh * TT * TT + idx] = val;
}

// ---------------- bias edge scatter ----------------
__global__ __launch_bounds__(256) void bias_scatter_kernel(const int* __restrict__ ei,
                                                           const int* __restrict__ ea,
                                                           const float* __restrict__ ebt,
                                                           float* __restrict__ biasT) {
    int e = blockIdx.x * 256 + threadIdx.x;
    if (e >= EE) return;
    int src = ei[e], dst = ei[EE + e];
    int g = src >> 9;                 // / NPG
    int sl = src - (g << 9) + 1;      // query index
    int dl = dst - (g << 9) + 1;      // key index
    int a = ea[e];
    a = (a < 0) ? 0 : (a > 9 ? 9 : a);
    a += 1;
    #pragma unroll
    for (int h = 0; h < HH; ++h) {
        // biasT[(g*H+h)][s=dl][q=sl]
        atomicAdd(&biasT[(((size_t)(g*HH + h)) * TT + dl) * TT + sl], ebt[a*HH + h]);
    }
}

// ---------------- LayerNorm (per row, C=128) ----------------
__global__ __launch_bounds__(128) void ln_kernel(const float* __restrict__ in,
                                                 float* __restrict__ out,
                                                 const float* __restrict__ gg,
                                                 const float* __restrict__ bb) {
    int row = blockIdx.x;
    int c = threadIdx.x;
    float v = in[(size_t)row * CC + c];
    float s1 = v, s2 = v * v;
    #pragma unroll
    for (int m = 32; m >= 1; m >>= 1) {
        s1 += __shfl_xor(s1, m, 64);
        s2 += __shfl_xor(s2, m, 64);
    }
    __shared__ float red[4];
    int w = c >> 6;
    if ((c & 63) == 0) { red[w*2] = s1; red[w*2+1] = s2; }
    __syncthreads();
    float S1 = red[0] + red[2], S2 = red[1] + red[3];
    float mn = S1 * (1.0f/CC);
    float var = S2 * (1.0f/CC) - mn * mn;
    float rs = rsqrtf(var + 1e-5f);
    out[(size_t)row * CC + c] = (v - mn) * rs * gg[c] + bb[c];
}

// ---------------- tiled f32 GEMM: out = A[M,K] @ W[K,N] + bias (+res / gelu) ----------------
// BM=64, BN=64, BK=16, 256 threads, 4x4 micro-tile.
// mode: 0 = bias only, 1 = bias + residual, 2 = bias + exact gelu
struct G3 {
    const float* W[3];
    const float* bias[3];
    float* out[3];
};

__global__ __launch_bounds__(256) void gemm64(const float* __restrict__ A, G3 p,
                                              const float* __restrict__ res,
                                              int M, int Nn, int K, int mode) {
    int z = blockIdx.z;
    const float* W = p.W[z];
    const float* bias = p.bias[z];
    float* out = p.out[z];

    int m0 = blockIdx.y * 64;
    int n0 = blockIdx.x * 64;
    __shared__ float As[16 * 80];   // [k][m], stride 80 keeps float4 reads 16B-aligned
    __shared__ float Ws[16 * 64];   // [k][n]

    int tid = threadIdx.x;
    int tx = tid & 15, ty = tid >> 4;
    int arow = tid >> 2, akq = tid & 3;   // A staging: row 0..63, k-quad 0..3
    int wk = tid >> 4, wn4 = tid & 15;    // W staging: k 0..15, n-quad 0..15

    float acc[4][4] = {};

    for (int kk = 0; kk < K; kk += 16) {
        float4 av = make_float4(0.f, 0.f, 0.f, 0.f);
        int gr = m0 + arow;
        if (gr < M) av = *(const float4*)(A + (size_t)gr * K + kk + akq * 4);
        As[(akq*4+0)*80 + arow] = av.x;
        As[(akq*4+1)*80 + arow] = av.y;
        As[(akq*4+2)*80 + arow] = av.z;
        As[(akq*4+3)*80 + arow] = av.w;
        float4 wv = *(const float4*)(W + (size_t)(kk + wk) * Nn + n0 + wn4 * 4);
        *(float4*)&Ws[wk*64 + wn4*4] = wv;
        __syncthreads();
        #pragma unroll
        for (int k = 0; k < 16; ++k) {
            float4 a4 = *(const float4*)&As[k*80 + ty*4];
            float4 w4 = *(const float4*)&Ws[k*64 + tx*4];
            float av_[4] = {a4.x, a4.y, a4.z, a4.w};
            float wv_[4] = {w4.x, w4.y, w4.z, w4.w};
            #pragma unroll
            for (int i = 0; i < 4; ++i)
                #pragma unroll
                for (int j = 0; j < 4; ++j)
                    acc[i][j] = fmaf(av_[i], wv_[j], acc[i][j]);
        }
        __syncthreads();
    }

    int col = n0 + tx * 4;
    float4 bv = *(const float4*)(bias + col);
    #pragma unroll
    for (int i = 0; i < 4; ++i) {
        int r = m0 + ty * 4 + i;
        if (r >= M) continue;
        float4 o;
        o.x = acc[i][0] + bv.x;
        o.y = acc[i][1] + bv.y;
        o.z = acc[i][2] + bv.z;
        o.w = acc[i][3] + bv.w;
        if (mode == 1) {
            float4 rv = *(const float4*)(res + (size_t)r * Nn + col);
            o.x += rv.x; o.y += rv.y; o.z += rv.z; o.w += rv.w;
        } else if (mode == 2) {
            o.x = gelu_exact(o.x); o.y = gelu_exact(o.y);
            o.z = gelu_exact(o.z); o.w = gelu_exact(o.w);
        }
        *(float4*)(out + (size_t)r * Nn + col) = o;
    }
}

// ---------------- fused attention: lane = (b,h,query) ----------------
__global__ __launch_bounds__(256) void attn_kernel(const float* __restrict__ qb,
                                                   const float* __restrict__ kb,
                                                   const float* __restrict__ vb,
                                                   const float* __restrict__ biasT,
                                                   float* __restrict__ ob) {
    int gid = blockIdx.x * 256 + threadIdx.x;
    if (gid >= BB * HH * TT) return;
    int bh = gid / TT;
    int qq = gid - bh * TT;
    int b = bh >> 3, h = bh & (HH - 1);

    const float4* qp = (const float4*)(qb + ((size_t)(b * TT + qq)) * CC + h * DD);
    float4 q0 = qp[0], q1 = qp[1], q2 = qp[2], q3 = qp[3];

    const float* kbase = kb + ((size_t)b * TT) * CC + h * DD;
    const float* vbase = vb + ((size_t)b * TT) * CC + h * DD;
    const float* brow = biasT + (size_t)bh * TT * TT + qq;

    float4 o0 = make_float4(0,0,0,0), o1 = o0, o2 = o0, o3 = o0;
    float l = 0.0f;
    const float scale = 0.25f;   // 1/sqrt(16)

    for (int s = 0; s < TT; ++s) {
        const float4* kp = (const float4*)(kbase + (size_t)s * CC);
        float4 k0 = kp[0], k1 = kp[1], k2 = kp[2], k3 = kp[3];
        float sc = dot4(q0,k0) + dot4(q1,k1) + dot4(q2,k2) + dot4(q3,k3);
        sc = sc * scale + brow[(size_t)s * TT];
        float pr = __expf(sc);   // scores bounded ~|6| -> safe without max-subtract
        l += pr;
        const float4* vp = (const float4*)(vbase + (size_t)s * CC);
        float4 v0 = vp[0], v1 = vp[1], v2 = vp[2], v3 = vp[3];
        fma4(o0, pr, v0); fma4(o1, pr, v1); fma4(o2, pr, v2); fma4(o3, pr, v3);
    }
    float inv = 1.0f / l;
    o0.x*=inv; o0.y*=inv; o0.z*=inv; o0.w*=inv;
    o1.x*=inv; o1.y*=inv; o1.z*=inv; o1.w*=inv;
    o2.x*=inv; o2.y*=inv; o2.z*=inv; o2.w*=inv;
    o3.x*=inv; o3.y*=inv; o3.z*=inv; o3.w*=inv;
    float4* op = (float4*)(ob + ((size_t)(b * TT + qq)) * CC + h * DD);
    op[0] = o0; op[1] = o1; op[2] = o2; op[3] = o3;
}

// ---------------- final LN on graph tokens + classifier ----------------
__global__ __launch_bounds__(128) void head_kernel(const float* __restrict__ x,
                                                   const float* __restrict__ ng,
                                                   const float* __restrict__ nb,
                                                   const float* __restrict__ Wc1,
                                                   const float* __restrict__ bc1,
                                                   const float* __restrict__ Wc2,
                                                   const float* __restrict__ bc2,
                                                   float* __restrict__ out) {
    int b = blockIdx.x;
    int c = threadIdx.x;   // 128
    __shared__ float xfs[CC];
    __shared__ float c1s[64];
    __shared__ float red[4];

    float v = x[((size_t)b * TT) * CC + c];
    float s1 = v, s2 = v * v;
    #pragma unroll
    for (int m = 32; m >= 1; m >>= 1) {
        s1 += __shfl_xor(s1, m, 64);
        s2 += __shfl_xor(s2, m, 64);
    }
    int w = c >> 6;
    if ((c & 63) == 0) { red[w*2] = s1; red[w*2+1] = s2; }
    __syncthreads();
    float S1 = red[0] + red[2], S2 = red[1] + red[3];
    float mn = S1 * (1.0f/CC);
    float var = S2 * (1.0f/CC) - mn * mn;
    float rs = rsqrtf(var + 1e-5f);
    xfs[c] = (v - mn) * rs * ng[c] + nb[c];
    __syncthreads();
    if (c < 64) {
        float a = bc1[c];
        #pragma unroll 4
        for (int k = 0; k < CC; ++k) a = fmaf(xfs[k], Wc1[(size_t)k * 64 + c], a);
        c1s[c] = gelu_exact(a);
    }
    __syncthreads();
    if (c < NCLS) {
        float a = bc2[c];
        #pragma unroll 4
        for (int j = 0; j < 64; ++j) a = fmaf(c1s[j], Wc2[(size_t)j * NCLS + c], a);
        out[(size_t)b * NCLS + c] = a;
    }
}

extern "C" void kernel_launch(void* const* d_in, const int* in_sizes, int n_in,
                              void* d_out, int out_size, void* d_ws, size_t ws_size,
                              hipStream_t stream) {
    const float* node_feats = (const float*)d_in[0];
    const int*   edge_index = (const int*)d_in[1];
    const int*   edge_attr  = (const int*)d_in[2];
    // d_in[3] = num_graphs (compile-time BB)
    const float* W_node  = (const float*)d_in[4];
    const float* b_node  = (const float*)d_in[5];
    const float* g_token = (const float*)d_in[6];
    const float* ebt     = (const float*)d_in[7];
    const float* ide     = (const float*)d_in[8];
    const float* ode     = (const float*)d_in[9];
    const float* vnode   = (const float*)d_in[10];
    const float* Wq = (const float*)d_in[11];
    const float* bq = (const float*)d_in[12];
    const float* Wk = (const float*)d_in[13];
    const float* bk = (const float*)d_in[14];
    const float* Wv = (const float*)d_in[15];
    const float* bv = (const float*)d_in[16];
    const float* Wo = (const float*)d_in[17];
    const float* bo = (const float*)d_in[18];
    const float* ln1g = (const float*)d_in[19];
    const float* ln1b = (const float*)d_in[20];
    const float* ln2g = (const float*)d_in[21];
    const float* ln2b = (const float*)d_in[22];
    const float* W1 = (const float*)d_in[23];
    const float* b1 = (const float*)d_in[24];
    const float* W2 = (const float*)d_in[25];
    const float* b2 = (const float*)d_in[26];
    const float* nfg = (const float*)d_in[27];
    const float* nfb = (const float*)d_in[28];
    const float* Wc1 = (const float*)d_in[29];
    const float* bc1 = (const float*)d_in[30];
    const float* Wc2 = (const float*)d_in[31];
    const float* bc2 = (const float*)d_in[32];
    float* out = (float*)d_out;

    float* ws    = (float*)d_ws;
    float* biasT = ws;
    float* x     = biasT + BIAS_SZ;
    float* hbuf  = x + XSZ;
    float* qb    = hbuf + XSZ;
    float* kb    = qb + XSZ;
    float* vb_   = kb + XSZ;
    float* ob    = vb_ + XSZ;
    float* mid   = ob + XSZ;
    int*   deg_in  = (int*)(mid + MIDSZ);
    int*   deg_out = deg_in + NNODES;

    hipMemsetAsync(deg_in, 0, 2 * NNODES * sizeof(int), stream);
    deg_kernel<<<EE / 256, 256, 0, stream>>>(edge_index, deg_in, deg_out);
    encode_kernel<<<(int)((XROWS * CC + 255) / 256), 256, 0, stream>>>(
        node_feats, W_node, b_node, g_token, ide, ode, deg_in, deg_out, x);
    bias_init_kernel<<<dim3((TT * TT + 255) / 256, BB * HH), 256, 0, stream>>>(vnode, biasT);
    bias_scatter_kernel<<<EE / 256, 256, 0, stream>>>(edge_index, edge_attr, ebt, biasT);

    const int GM = (int)((XROWS + 63) / 64);   // 129

    for (int l = 0; l < LL; ++l) {
        ln_kernel<<<(int)XROWS, 128, 0, stream>>>(x, hbuf, ln1g + l*CC, ln1b + l*CC);

        G3 pq = {};
        pq.W[0] = Wq + (size_t)l*CC*CC; pq.W[1] = Wk + (size_t)l*CC*CC; pq.W[2] = Wv + (size_t)l*CC*CC;
        pq.bias[0] = bq + l*CC; pq.bias[1] = bk + l*CC; pq.bias[2] = bv + l*CC;
        pq.out[0] = qb; pq.out[1] = kb; pq.out[2] = vb_;
        gemm64<<<dim3(2, GM, 3), 256, 0, stream>>>(hbuf, pq, nullptr, (int)XROWS, CC, CC, 0);

        attn_kernel<<<(BB*HH*TT + 255) / 256, 256, 0, stream>>>(qb, kb, vb_, biasT, ob);

        G3 po = {};
        po.W[0] = Wo + (size_t)l*CC*CC; po.bias[0] = bo + l*CC; po.out[0] = x;
        gemm64<<<dim3(2, GM, 1), 256, 0, stream>>>(ob, po, x, (int)XROWS, CC, CC, 1);

        ln_kernel<<<(int)XROWS, 128, 0, stream>>>(x, hbuf, ln2g + l*CC, ln2b + l*CC);

        G3 p1 = {};
        p1.W[0] = W1 + (size_t)l*CC*FFN; p1.bias[0] = b1 + l*FFN; p1.out[0] = mid;
        gemm64<<<dim3(8, GM, 1), 256, 0, stream>>>(hbuf, p1, nullptr, (int)XROWS, FFN, CC, 2);

        G3 p2 = {};
        p2.W[0] = W2 + (size_t)l*FFN*CC; p2.bias[0] = b2 + l*CC; p2.out[0] = x;
        gemm64<<<dim3(2, GM, 1), 256, 0, stream>>>(mid, p2, x, (int)XROWS, CC, FFN, 1);
    }

    head_kernel<<<BB, 128, 0, stream>>>(x, nfg, nfb, Wc1, bc1, Wc2, bc2, out);
}

// Round 2
// 1232.880 us; speedup vs baseline: 1.5798x; 1.5798x over previous
//
#include <hip/hip_runtime.h>
#include <hip/hip_bf16.h>

#define BB 16
#define NPG 512
#define CC 128
#define HH 8
#define LL 4
#define FFN 512
#define NCLS 4
#define DD 16
#define TT 513            // NPG + 1
#define EE 131072         // B * 8192
#define NNODES 8192       // B * NPG

static constexpr size_t BIAS_SZ = (size_t)BB * HH * TT * TT;   // 33,685,632
static constexpr size_t XROWS   = (size_t)BB * TT;             // 8208
static constexpr size_t XSZ     = XROWS * CC;                  // 1,050,624
static constexpr size_t MIDSZ   = XROWS * FFN;                 // 4,202,496

__device__ __forceinline__ float gelu_exact(float v) {
    return 0.5f * v * (1.0f + erff(v * 0.70710678118654752440f));
}
__device__ __forceinline__ float dot4(float4 a, float4 b) {
    return a.x*b.x + a.y*b.y + a.z*b.z + a.w*b.w;
}
__device__ __forceinline__ void fma4(float4& o, float p, float4 v) {
    o.x = fmaf(p, v.x, o.x); o.y = fmaf(p, v.y, o.y);
    o.z = fmaf(p, v.z, o.z); o.w = fmaf(p, v.w, o.w);
}

// ---------------- degree count ----------------
__global__ __launch_bounds__(256) void deg_kernel(const int* __restrict__ ei,
                                                  int* __restrict__ deg_in,
                                                  int* __restrict__ deg_out) {
    int e = blockIdx.x * 256 + threadIdx.x;
    if (e >= EE) return;
    atomicAdd(&deg_out[ei[e]], 1);
    atomicAdd(&deg_in[ei[EE + e]], 1);
}

// ---------------- node encode + graph token ----------------
__global__ __launch_bounds__(256) void encode_kernel(const float* __restrict__ nf,
                                                     const float* __restrict__ Wn,
                                                     const float* __restrict__ bn,
                                                     const float* __restrict__ gt,
                                                     const float* __restrict__ ide,
                                                     const float* __restrict__ ode,
                                                     const int* __restrict__ deg_in,
                                                     const int* __restrict__ deg_out,
                                                     float* __restrict__ x) {
    int gid = blockIdx.x * 256 + threadIdx.x;
    if (gid >= (int)(XROWS * CC)) return;
    int c = gid & (CC - 1);
    int row = gid >> 7;
    int b = row / TT;
    int t = row - b * TT;
    float val;
    if (t == 0) {
        val = gt[c];
    } else {
        int i = b * NPG + t - 1;
        val = bn[c] + nf[i*3+0]*Wn[0*CC + c] + nf[i*3+1]*Wn[1*CC + c] + nf[i*3+2]*Wn[2*CC + c];
        int di = min(deg_in[i], 511);
        int dq = min(deg_out[i], 511);
        val += ide[(size_t)di * CC + c] + ode[(size_t)dq * CC + c];
    }
    x[(size_t)row * CC + c] = val;
}

// ---------------- bias init: biasT[bh][s][q] ----------------
__global__ __launch_bounds__(256) void bias_init_kernel(const float* __restrict__ vb,
                                                        float* __restrict__ biasT) {
    int bh = blockIdx.y;
    int idx = blockIdx.x * 256 + threadIdx.x;
    if (idx >= TT * TT) return;
    int s = idx / TT;
    int q = idx - s * TT;
    float val = (s == 0 || q == 0) ? vb[bh & (HH - 1)] : 0.0f;
    biasT[(size_t)bh * TT * TT + idx] = val;
}

// ---------------- bias edge scatter ----------------
__global__ __launch_bounds__(256) void bias_scatter_kernel(const int* __restrict__ ei,
                                                           const int* __restrict__ ea,
                                                           const float* __restrict__ ebt,
                                                           float* __restrict__ biasT) {
    int e = blockIdx.x * 256 + threadIdx.x;
    if (e >= EE) return;
    int src = ei[e], dst = ei[EE + e];
    int g = src >> 9;                 // / NPG
    int sl = src - (g << 9) + 1;      // query index
    int dl = dst - (g << 9) + 1;      // key index
    int a = ea[e];
    a = (a < 0) ? 0 : (a > 9 ? 9 : a);
    a += 1;
    #pragma unroll
    for (int h = 0; h < HH; ++h) {
        // biasT[(g*H+h)][s=dl][q=sl]
        atomicAdd(&biasT[(((size_t)(g*HH + h)) * TT + dl) * TT + sl], ebt[a*HH + h]);
    }
}

// ---------------- LayerNorm (per row, C=128) ----------------
__global__ __launch_bounds__(128) void ln_kernel(const float* __restrict__ in,
                                                 float* __restrict__ out,
                                                 const float* __restrict__ gg,
                                                 const float* __restrict__ bb) {
    int row = blockIdx.x;
    int c = threadIdx.x;
    float v = in[(size_t)row * CC + c];
    float s1 = v, s2 = v * v;
    #pragma unroll
    for (int m = 32; m >= 1; m >>= 1) {
        s1 += __shfl_xor(s1, m, 64);
        s2 += __shfl_xor(s2, m, 64);
    }
    __shared__ float red[4];
    int w = c >> 6;
    if ((c & 63) == 0) { red[w*2] = s1; red[w*2+1] = s2; }
    __syncthreads();
    float S1 = red[0] + red[2], S2 = red[1] + red[3];
    float mn = S1 * (1.0f/CC);
    float var = S2 * (1.0f/CC) - mn * mn;
    float rs = rsqrtf(var + 1e-5f);
    out[(size_t)row * CC + c] = (v - mn) * rs * gg[c] + bb[c];
}

// ---------------- tiled f32 GEMM: out = A[M,K] @ W[K,N] + bias (+res / gelu) ----------------
// BM=64, BN=64, BK=16, 256 threads, 4x4 micro-tile.
// mode: 0 = bias only, 1 = bias + residual, 2 = bias + exact gelu
struct G3 {
    const float* W[3];
    const float* bias[3];
    float* out[3];
};

__global__ __launch_bounds__(256) void gemm64(const float* __restrict__ A, G3 p,
                                              const float* __restrict__ res,
                                              int M, int Nn, int K, int mode) {
    int z = blockIdx.z;
    const float* W = p.W[z];
    const float* bias = p.bias[z];
    float* out = p.out[z];

    int m0 = blockIdx.y * 64;
    int n0 = blockIdx.x * 64;
    __shared__ float As[16 * 80];   // [k][m], stride 80 keeps float4 reads 16B-aligned
    __shared__ float Ws[16 * 64];   // [k][n]

    int tid = threadIdx.x;
    int tx = tid & 15, ty = tid >> 4;
    int arow = tid >> 2, akq = tid & 3;   // A staging: row 0..63, k-quad 0..3
    int wk = tid >> 4, wn4 = tid & 15;    // W staging: k 0..15, n-quad 0..15

    float acc[4][4] = {};

    for (int kk = 0; kk < K; kk += 16) {
        float4 av = make_float4(0.f, 0.f, 0.f, 0.f);
        int gr = m0 + arow;
        if (gr < M) av = *(const float4*)(A + (size_t)gr * K + kk + akq * 4);
        As[(akq*4+0)*80 + arow] = av.x;
        As[(akq*4+1)*80 + arow] = av.y;
        As[(akq*4+2)*80 + arow] = av.z;
        As[(akq*4+3)*80 + arow] = av.w;
        float4 wv = *(const float4*)(W + (size_t)(kk + wk) * Nn + n0 + wn4 * 4);
        *(float4*)&Ws[wk*64 + wn4*4] = wv;
        __syncthreads();
        #pragma unroll
        for (int k = 0; k < 16; ++k) {
            float4 a4 = *(const float4*)&As[k*80 + ty*4];
            float4 w4 = *(const float4*)&Ws[k*64 + tx*4];
            float av_[4] = {a4.x, a4.y, a4.z, a4.w};
            float wv_[4] = {w4.x, w4.y, w4.z, w4.w};
            #pragma unroll
            for (int i = 0; i < 4; ++i)
                #pragma unroll
                for (int j = 0; j < 4; ++j)
                    acc[i][j] = fmaf(av_[i], wv_[j], acc[i][j]);
        }
        __syncthreads();
    }

    int col = n0 + tx * 4;
    float4 bv = *(const float4*)(bias + col);
    #pragma unroll
    for (int i = 0; i < 4; ++i) {
        int r = m0 + ty * 4 + i;
        if (r >= M) continue;
        float4 o;
        o.x = acc[i][0] + bv.x;
        o.y = acc[i][1] + bv.y;
        o.z = acc[i][2] + bv.z;
        o.w = acc[i][3] + bv.w;
        if (mode == 1) {
            float4 rv = *(const float4*)(res + (size_t)r * Nn + col);
            o.x += rv.x; o.y += rv.y; o.z += rv.z; o.w += rv.w;
        } else if (mode == 2) {
            o.x = gelu_exact(o.x); o.y = gelu_exact(o.y);
            o.z = gelu_exact(o.z); o.w = gelu_exact(o.w);
        }
        *(float4*)(out + (size_t)r * Nn + col) = o;
    }
}

// ---------------- split-key fused attention ----------------
// Block: 512 threads = 8 waves. blockIdx.x = bh (128), blockIdx.y = q-tile (9).
// Wave p handles keys s = p, p+8, p+16, ... ; lane = query within 64-query tile.
// K/V reads are wave-broadcast (L1); bias reads coalesced (biasT[bh][s][q]).
// Partials (16 o + 1 expsum per lane) reduced across the 8 waves via LDS.
__global__ __launch_bounds__(512) void attn_split_kernel(const float* __restrict__ qb,
                                                         const float* __restrict__ kb,
                                                         const float* __restrict__ vb,
                                                         const float* __restrict__ biasT,
                                                         float* __restrict__ ob) {
    int bh = blockIdx.x;
    int q0 = blockIdx.y * 64;
    int b = bh >> 3, h = bh & (HH - 1);
    int tid = threadIdx.x;
    int p = tid >> 6;          // wave / key-segment 0..7
    int lane = tid & 63;       // query within tile
    int q = q0 + lane;
    bool qv = q < TT;
    int qc = qv ? q : TT - 1;

    __shared__ float part[8 * 64 * 17];   // [p][q][16 o + 1 l], stride 17 breaks conflicts
    __shared__ float lred[64];

    const float4* qp = (const float4*)(qb + ((size_t)(b * TT + qc)) * CC + h * DD);
    float4 Q0 = qp[0], Q1 = qp[1], Q2 = qp[2], Q3 = qp[3];

    const float* kbase = kb + (size_t)b * TT * CC + h * DD;
    const float* vbase = vb + (size_t)b * TT * CC + h * DD;
    const float* bbase = biasT + (size_t)bh * TT * TT;

    float4 o0 = make_float4(0,0,0,0), o1 = o0, o2 = o0, o3 = o0;
    float l = 0.0f;

    for (int s = p; s < TT; s += 8) {
        float bi = qv ? bbase[(size_t)s * TT + q] : 0.0f;
        const float4* kp = (const float4*)(kbase + (size_t)s * CC);
        float sc = dot4(Q0, kp[0]) + dot4(Q1, kp[1]) + dot4(Q2, kp[2]) + dot4(Q3, kp[3]);
        float pr = __expf(fmaf(sc, 0.25f, bi));   // scores bounded, no max-subtract needed
        l += pr;
        const float4* vp = (const float4*)(vbase + (size_t)s * CC);
        fma4(o0, pr, vp[0]); fma4(o1, pr, vp[1]);
        fma4(o2, pr, vp[2]); fma4(o3, pr, vp[3]);
    }

    float* mp = &part[(p * 64 + lane) * 17];
    mp[0]=o0.x;  mp[1]=o0.y;  mp[2]=o0.z;  mp[3]=o0.w;
    mp[4]=o1.x;  mp[5]=o1.y;  mp[6]=o1.z;  mp[7]=o1.w;
    mp[8]=o2.x;  mp[9]=o2.y;  mp[10]=o2.z; mp[11]=o2.w;
    mp[12]=o3.x; mp[13]=o3.y; mp[14]=o3.z; mp[15]=o3.w;
    mp[16]=l;
    __syncthreads();

    // reduce 1024 o-values (2 per thread) + 64 expsums across the 8 segments
    int idx0 = tid, idx1 = tid + 512;
    int qa0 = idx0 >> 4, da0 = idx0 & 15;
    int qa1 = idx1 >> 4, da1 = idx1 & 15;
    float r0 = 0.0f, r1 = 0.0f;
    #pragma unroll
    for (int pp = 0; pp < 8; ++pp) {
        r0 += part[pp * 1088 + qa0 * 17 + da0];
        r1 += part[pp * 1088 + qa1 * 17 + da1];
    }
    if (tid < 64) {
        float ls = 0.0f;
        #pragma unroll
        for (int pp = 0; pp < 8; ++pp) ls += part[pp * 1088 + tid * 17 + 16];
        lred[tid] = 1.0f / ls;
    }
    __syncthreads();

    int qg0 = q0 + qa0;
    if (qg0 < TT) ob[((size_t)(b * TT + qg0)) * CC + h * DD + da0] = r0 * lred[qa0];
    int qg1 = q0 + qa1;
    if (qg1 < TT) ob[((size_t)(b * TT + qg1)) * CC + h * DD + da1] = r1 * lred[qa1];
}

// ---------------- final LN on graph tokens + classifier ----------------
__global__ __launch_bounds__(128) void head_kernel(const float* __restrict__ x,
                                                   const float* __restrict__ ng,
                                                   const float* __restrict__ nb,
                                                   const float* __restrict__ Wc1,
                                                   const float* __restrict__ bc1,
                                                   const float* __restrict__ Wc2,
                                                   const float* __restrict__ bc2,
                                                   float* __restrict__ out) {
    int b = blockIdx.x;
    int c = threadIdx.x;   // 128
    __shared__ float xfs[CC];
    __shared__ float c1s[64];
    __shared__ float red[4];

    float v = x[((size_t)b * TT) * CC + c];
    float s1 = v, s2 = v * v;
    #pragma unroll
    for (int m = 32; m >= 1; m >>= 1) {
        s1 += __shfl_xor(s1, m, 64);
        s2 += __shfl_xor(s2, m, 64);
    }
    int w = c >> 6;
    if ((c & 63) == 0) { red[w*2] = s1; red[w*2+1] = s2; }
    __syncthreads();
    float S1 = red[0] + red[2], S2 = red[1] + red[3];
    float mn = S1 * (1.0f/CC);
    float var = S2 * (1.0f/CC) - mn * mn;
    float rs = rsqrtf(var + 1e-5f);
    xfs[c] = (v - mn) * rs * ng[c] + nb[c];
    __syncthreads();
    if (c < 64) {
        float a = bc1[c];
        #pragma unroll 4
        for (int k = 0; k < CC; ++k) a = fmaf(xfs[k], Wc1[(size_t)k * 64 + c], a);
        c1s[c] = gelu_exact(a);
    }
    __syncthreads();
    if (c < NCLS) {
        float a = bc2[c];
        #pragma unroll 4
        for (int j = 0; j < 64; ++j) a = fmaf(c1s[j], Wc2[(size_t)j * NCLS + c], a);
        out[(size_t)b * NCLS + c] = a;
    }
}

extern "C" void kernel_launch(void* const* d_in, const int* in_sizes, int n_in,
                              void* d_out, int out_size, void* d_ws, size_t ws_size,
                              hipStream_t stream) {
    const float* node_feats = (const float*)d_in[0];
    const int*   edge_index = (const int*)d_in[1];
    const int*   edge_attr  = (const int*)d_in[2];
    // d_in[3] = num_graphs (compile-time BB)
    const float* W_node  = (const float*)d_in[4];
    const float* b_node  = (const float*)d_in[5];
    const float* g_token = (const float*)d_in[6];
    const float* ebt     = (const float*)d_in[7];
    const float* ide     = (const float*)d_in[8];
    const float* ode     = (const float*)d_in[9];
    const float* vnode   = (const float*)d_in[10];
    const float* Wq = (const float*)d_in[11];
    const float* bq = (const float*)d_in[12];
    const float* Wk = (const float*)d_in[13];
    const float* bk = (const float*)d_in[14];
    const float* Wv = (const float*)d_in[15];
    const float* bv = (const float*)d_in[16];
    const float* Wo = (const float*)d_in[17];
    const float* bo = (const float*)d_in[18];
    const float* ln1g = (const float*)d_in[19];
    const float* ln1b = (const float*)d_in[20];
    const float* ln2g = (const float*)d_in[21];
    const float* ln2b = (const float*)d_in[22];
    const float* W1 = (const float*)d_in[23];
    const float* b1 = (const float*)d_in[24];
    const float* W2 = (const float*)d_in[25];
    const float* b2 = (const float*)d_in[26];
    const float* nfg = (const float*)d_in[27];
    const float* nfb = (const float*)d_in[28];
    const float* Wc1 = (const float*)d_in[29];
    const float* bc1 = (const float*)d_in[30];
    const float* Wc2 = (const float*)d_in[31];
    const float* bc2 = (const float*)d_in[32];
    float* out = (float*)d_out;

    float* ws    = (float*)d_ws;
    float* biasT = ws;
    float* x     = biasT + BIAS_SZ;
    float* hbuf  = x + XSZ;
    float* qb    = hbuf + XSZ;
    float* kb    = qb + XSZ;
    float* vb_   = kb + XSZ;
    float* ob    = vb_ + XSZ;
    float* mid   = ob + XSZ;
    int*   deg_in  = (int*)(mid + MIDSZ);
    int*   deg_out = deg_in + NNODES;

    hipMemsetAsync(deg_in, 0, 2 * NNODES * sizeof(int), stream);
    deg_kernel<<<EE / 256, 256, 0, stream>>>(edge_index, deg_in, deg_out);
    encode_kernel<<<(int)((XROWS * CC + 255) / 256), 256, 0, stream>>>(
        node_feats, W_node, b_node, g_token, ide, ode, deg_in, deg_out, x);
    bias_init_kernel<<<dim3((TT * TT + 255) / 256, BB * HH), 256, 0, stream>>>(vnode, biasT);
    bias_scatter_kernel<<<EE / 256, 256, 0, stream>>>(edge_index, edge_attr, ebt, biasT);

    const int GM = (int)((XROWS + 63) / 64);   // 129

    for (int l = 0; l < LL; ++l) {
        ln_kernel<<<(int)XROWS, 128, 0, stream>>>(x, hbuf, ln1g + l*CC, ln1b + l*CC);

        G3 pq = {};
        pq.W[0] = Wq + (size_t)l*CC*CC; pq.W[1] = Wk + (size_t)l*CC*CC; pq.W[2] = Wv + (size_t)l*CC*CC;
        pq.bias[0] = bq + l*CC; pq.bias[1] = bk + l*CC; pq.bias[2] = bv + l*CC;
        pq.out[0] = qb; pq.out[1] = kb; pq.out[2] = vb_;
        gemm64<<<dim3(2, GM, 3), 256, 0, stream>>>(hbuf, pq, nullptr, (int)XROWS, CC, CC, 0);

        attn_split_kernel<<<dim3(BB*HH, (TT + 63) / 64), 512, 0, stream>>>(qb, kb, vb_, biasT, ob);

        G3 po = {};
        po.W[0] = Wo + (size_t)l*CC*CC; po.bias[0] = bo + l*CC; po.out[0] = x;
        gemm64<<<dim3(2, GM, 1), 256, 0, stream>>>(ob, po, x, (int)XROWS, CC, CC, 1);

        ln_kernel<<<(int)XROWS, 128, 0, stream>>>(x, hbuf, ln2g + l*CC, ln2b + l*CC);

        G3 p1 = {};
        p1.W[0] = W1 + (size_t)l*CC*FFN; p1.bias[0] = b1 + l*FFN; p1.out[0] = mid;
        gemm64<<<dim3(8, GM, 1), 256, 0, stream>>>(hbuf, p1, nullptr, (int)XROWS, FFN, CC, 2);

        G3 p2 = {};
        p2.W[0] = W2 + (size_t)l*FFN*CC; p2.bias[0] = b2 + l*CC; p2.out[0] = x;
        gemm64<<<dim3(2, GM, 1), 256, 0, stream>>>(mid, p2, x, (int)XROWS, CC, FFN, 1);
    }

    head_kernel<<<BB, 128, 0, stream>>>(x, nfg, nfb, Wc1, bc1, Wc2, bc2, out);
}